// Round 1
// baseline (86.330 us; speedup 1.0000x reference)
//
#include <hip/hip_runtime.h>

// Inclusive prefix-compose of rigid transforms along N=32 per batch row.
// x: float[B][32][3][4]  (r = cols 0..2, t = col 3)
// out[b][n] = x[b][0] * x[b][1] * ... * x[b][n]   (4x4 homogeneous product)
//
// Mapping: lane (threadIdx & 31) = sequence position n; 2 rows per wave64.
// Hillis-Steele scan over 32-lane segments via __shfl_up(width=32).

__global__ __launch_bounds__(256) void compose_scan_kernel(
    const float* __restrict__ x, float* __restrict__ out, int nrows)
{
    const int t = blockIdx.x * blockDim.x + threadIdx.x;
    const int b = t >> 5;          // batch row
    const int n = t & 31;          // sequence position
    if (b >= nrows) return;

    const size_t base = ((size_t)b * 32 + (size_t)n) * 12;

    // Load one 3x4 transform: row-major, r[i][j]=e[i*4+j], t[i]=e[i*4+3]
    float4 v0 = *reinterpret_cast<const float4*>(x + base);
    float4 v1 = *reinterpret_cast<const float4*>(x + base + 4);
    float4 v2 = *reinterpret_cast<const float4*>(x + base + 8);

    float r00 = v0.x, r01 = v0.y, r02 = v0.z, tx = v0.w;
    float r10 = v1.x, r11 = v1.y, r12 = v1.z, ty = v1.w;
    float r20 = v2.x, r21 = v2.y, r22 = v2.z, tz = v2.w;

    // Inclusive scan: after step d, lane n holds product x[n-span+1..n].
    #pragma unroll
    for (int d = 1; d < 32; d <<= 1) {
        // U = prefix from lane n-d (left operand), V = current value.
        float u00 = __shfl_up(r00, (unsigned)d, 32);
        float u01 = __shfl_up(r01, (unsigned)d, 32);
        float u02 = __shfl_up(r02, (unsigned)d, 32);
        float u10 = __shfl_up(r10, (unsigned)d, 32);
        float u11 = __shfl_up(r11, (unsigned)d, 32);
        float u12 = __shfl_up(r12, (unsigned)d, 32);
        float u20 = __shfl_up(r20, (unsigned)d, 32);
        float u21 = __shfl_up(r21, (unsigned)d, 32);
        float u22 = __shfl_up(r22, (unsigned)d, 32);
        float sx  = __shfl_up(tx,  (unsigned)d, 32);
        float sy  = __shfl_up(ty,  (unsigned)d, 32);
        float sz  = __shfl_up(tz,  (unsigned)d, 32);

        if (n >= d) {
            // new = U o V:  r = rU@rV,  t = tU + rU@tV
            float n00 = u00 * r00 + u01 * r10 + u02 * r20;
            float n01 = u00 * r01 + u01 * r11 + u02 * r21;
            float n02 = u00 * r02 + u01 * r12 + u02 * r22;
            float n10 = u10 * r00 + u11 * r10 + u12 * r20;
            float n11 = u10 * r01 + u11 * r11 + u12 * r21;
            float n12 = u10 * r02 + u11 * r12 + u12 * r22;
            float n20 = u20 * r00 + u21 * r10 + u22 * r20;
            float n21 = u20 * r01 + u21 * r11 + u22 * r21;
            float n22 = u20 * r02 + u21 * r12 + u22 * r22;
            float ntx = sx + u00 * tx + u01 * ty + u02 * tz;
            float nty = sy + u10 * tx + u11 * ty + u12 * tz;
            float ntz = sz + u20 * tx + u21 * ty + u22 * tz;

            r00 = n00; r01 = n01; r02 = n02;
            r10 = n10; r11 = n11; r12 = n12;
            r20 = n20; r21 = n21; r22 = n22;
            tx  = ntx; ty  = nty; tz  = ntz;
        }
    }

    float4 o0 = make_float4(r00, r01, r02, tx);
    float4 o1 = make_float4(r10, r11, r12, ty);
    float4 o2 = make_float4(r20, r21, r22, tz);
    *reinterpret_cast<float4*>(out + base)     = o0;
    *reinterpret_cast<float4*>(out + base + 4) = o1;
    *reinterpret_cast<float4*>(out + base + 8) = o2;
}

extern "C" void kernel_launch(void* const* d_in, const int* in_sizes, int n_in,
                              void* d_out, int out_size, void* d_ws, size_t ws_size,
                              hipStream_t stream) {
    const float* x = (const float*)d_in[0];
    float* out = (float*)d_out;

    const int nrows = in_sizes[0] / (32 * 12);   // B
    const int total_threads = nrows * 32;
    const int block = 256;
    const int grid = (total_threads + block - 1) / block;

    compose_scan_kernel<<<grid, block, 0, stream>>>(x, out, nrows);
}